// Round 1
// baseline (8091.988 us; speedup 1.0000x reference)
//
#include <hip/hip_runtime.h>
#include <stdint.h>

#define DEPTH 512
#define INSZ  256
#define SSZ   4096
#define NSC   8

typedef unsigned int  u32;
typedef unsigned short u16;

// ---------- helpers ----------
__device__ __forceinline__ float bflo(u32 u) { return __uint_as_float(u << 16); }
__device__ __forceinline__ float bfhi(u32 u) { return __uint_as_float(u & 0xffff0000u); }

__device__ __forceinline__ u32 f2bf_rne(float f) {
    u32 u = __float_as_uint(f);
    return (u + 0x7fffu + ((u >> 16) & 1u)) >> 16;   // RNE, inputs are finite randn
}

// ---------- prep: W_lin f32 -> bf16 (packed 2/u32) ----------
__global__ __launch_bounds__(256) void conv_w(const float* __restrict__ W,
                                              u32* __restrict__ Wb) {
    int idx = blockIdx.x * 256 + threadIdx.x;          // 4096*4096/4 = 4,194,304 threads
    float4 v = reinterpret_cast<const float4*>(W)[idx];
    uint2 o;
    o.x = (f2bf_rne(v.y) << 16) | f2bf_rne(v.x);
    o.y = (f2bf_rne(v.w) << 16) | f2bf_rne(v.z);
    reinterpret_cast<uint2*>(Wb)[idx] = o;
}

// ---------- prep: cur0[s][i] = state[i] ----------
__global__ __launch_bounds__(256) void init_cur(const float* __restrict__ state,
                                                float* __restrict__ cur) {
    int idx = blockIdx.x * 256 + threadIdx.x;          // 32768
    cur[idx] = state[idx & (SSZ - 1)];
}

// ---------- biases[n][i] = sum_j W_in[i][j] * seq[n][j]  (f32) ----------
__global__ __launch_bounds__(256) void bias_kernel(const float* __restrict__ W_in,
                                                   const float* __restrict__ seq,
                                                   float* __restrict__ biases) {
    __shared__ float s_w[32][257];    // +1 pad: conflict-free reads across i
    __shared__ float s_seq[8][260];   // +4 pad: conflict-free reads across n
    const int i0 = blockIdx.x * 32;
    const int n0 = blockIdx.y * 8;
    const int tid = threadIdx.x;

    for (int idx = tid; idx < 32 * 256; idx += 256) {
        int r = idx >> 8, j = idx & 255;
        s_w[r][j] = W_in[(i0 + r) * INSZ + j];
    }
    for (int idx = tid; idx < 8 * 256; idx += 256) {
        int r = idx >> 8, j = idx & 255;
        s_seq[r][j] = seq[(n0 + r) * INSZ + j];
    }
    __syncthreads();

    const int i_loc = tid >> 3, n_loc = tid & 7;
    float acc = 0.f;
    #pragma unroll 8
    for (int j = 0; j < 256; ++j)
        acc = fmaf(s_w[i_loc][j], s_seq[n_loc][j], acc);
    biases[(size_t)(n0 + n_loc) * SSZ + i0 + i_loc] = acc;
}

// ---------- one recurrence step ----------
// grid 256 blocks x 256 thr; block owns 16 rows; wave w -> rows r0..r0+3;
// lanes K-split (64 x 64 j); full cur staged in LDS (f32, 128 KB).
__global__ __launch_bounds__(256) void step_kernel(const u16* __restrict__ Wb,
                                                   const float* __restrict__ biases,
                                                   const float* __restrict__ scales,
                                                   const float* __restrict__ cur,
                                                   float* __restrict__ nxt,
                                                   float* __restrict__ out,
                                                   int t) {
    __shared__ float s_cur[NSC * SSZ];   // 131072 B
    const int tid = threadIdx.x;

    {   // stage cur: 32768 f32 = 8192 float4, 32 per thread, coalesced
        const float4* src = reinterpret_cast<const float4*>(cur);
        float4* dst = reinterpret_cast<float4*>(s_cur);
        #pragma unroll
        for (int k = 0; k < 32; ++k)
            dst[k * 256 + tid] = src[k * 256 + tid];
    }
    __syncthreads();

    const int w = tid >> 6, l = tid & 63;
    const int r0 = blockIdx.x * 16 + w * 4;

    float acc[4][8];
    #pragma unroll
    for (int ri = 0; ri < 4; ++ri)
        #pragma unroll
        for (int s = 0; s < 8; ++s) acc[ri][s] = 0.f;

    // lane covers j in {c*512 + l*4 .. +3} U {c*512 + 256 + l*4 .. +3}, c = 0..7
    #pragma unroll 2
    for (int c = 0; c < 8; ++c) {
        const int jA = c * 512 + l * 4;
        const int jB = jA + 256;
        float wvA[4][4], wvB[4][4];
        #pragma unroll
        for (int ri = 0; ri < 4; ++ri) {
            const u16* rp = Wb + (size_t)(r0 + ri) * SSZ;
            uint2 a = *reinterpret_cast<const uint2*>(rp + jA);
            uint2 b = *reinterpret_cast<const uint2*>(rp + jB);
            wvA[ri][0] = bflo(a.x); wvA[ri][1] = bfhi(a.x);
            wvA[ri][2] = bflo(a.y); wvA[ri][3] = bfhi(a.y);
            wvB[ri][0] = bflo(b.x); wvB[ri][1] = bfhi(b.x);
            wvB[ri][2] = bflo(b.y); wvB[ri][3] = bfhi(b.y);
        }
        #pragma unroll
        for (int s = 0; s < 8; ++s) {
            const float* cp = &s_cur[s * SSZ];
            float4 ca = *reinterpret_cast<const float4*>(cp + jA);
            float4 cb = *reinterpret_cast<const float4*>(cp + jB);
            #pragma unroll
            for (int ri = 0; ri < 4; ++ri) {
                acc[ri][s] = fmaf(wvA[ri][0], ca.x, acc[ri][s]);
                acc[ri][s] = fmaf(wvA[ri][1], ca.y, acc[ri][s]);
                acc[ri][s] = fmaf(wvA[ri][2], ca.z, acc[ri][s]);
                acc[ri][s] = fmaf(wvA[ri][3], ca.w, acc[ri][s]);
                acc[ri][s] = fmaf(wvB[ri][0], cb.x, acc[ri][s]);
                acc[ri][s] = fmaf(wvB[ri][1], cb.y, acc[ri][s]);
                acc[ri][s] = fmaf(wvB[ri][2], cb.z, acc[ri][s]);
                acc[ri][s] = fmaf(wvB[ri][3], cb.w, acc[ri][s]);
            }
        }
    }

    // butterfly all-reduce over the 64-lane K-split
    #pragma unroll
    for (int ri = 0; ri < 4; ++ri)
        #pragma unroll
        for (int s = 0; s < 8; ++s)
            for (int off = 32; off > 0; off >>= 1)
                acc[ri][s] += __shfl_xor(acc[ri][s], off, 64);

    if (l < 32) {
        const int ri = l >> 3, s = l & 7;
        float v = 0.f;
        #pragma unroll
        for (int a = 0; a < 4; ++a)
            #pragma unroll
            for (int b = 0; b < 8; ++b)
                v = (l == a * 8 + b) ? acc[a][b] : v;   // compile-time indexed select
        const int row = r0 + ri;
        float pre = scales[s] * v + biases[(size_t)t * SSZ + row];
        float o = erff(pre) * 0.015625f;                // 1/sqrt(4096)
        out[((size_t)s << 21) + ((size_t)t << 12) + row] = o;
        nxt[(s << 12) + row] = o;
    }
}

// ---------- launch ----------
extern "C" void kernel_launch(void* const* d_in, const int* in_sizes, int n_in,
                              void* d_out, int out_size, void* d_ws, size_t ws_size,
                              hipStream_t stream) {
    const float* seq    = (const float*)d_in[0];   // (512, 256)
    const float* state  = (const float*)d_in[1];   // (4096,)
    const float* W_in   = (const float*)d_in[2];   // (4096, 256)
    const float* W_lin  = (const float*)d_in[3];   // (4096, 4096)
    const float* scales = (const float*)d_in[4];   // (8,)
    float* out = (float*)d_out;                    // (8, 512, 4096) f32

    char* ws = (char*)d_ws;
    u32*   Wb     = (u32*)(ws);                          // 33,554,432 B  (bf16 W)
    float* biases = (float*)(ws + 33554432);             //  8,388,608 B
    float* curA   = (float*)(ws + 41943040);             //    131,072 B
    float* curB   = (float*)(ws + 41943040 + 131072);    //    131,072 B

    conv_w   <<<16384, 256, 0, stream>>>(W_lin, Wb);
    init_cur <<<128,   256, 0, stream>>>(state, curA);
    bias_kernel<<<dim3(128, 64), 256, 0, stream>>>(W_in, seq, biases);

    float* a = curA;
    float* b = curB;
    for (int t = 0; t < DEPTH; ++t) {
        step_kernel<<<256, 256, 0, stream>>>((const u16*)Wb, biases, scales,
                                             a, b, out, t);
        float* tmp = a; a = b; b = tmp;
    }
}